// Round 4
// baseline (317.309 us; speedup 1.0000x reference)
//
#include <hip/hip_runtime.h>

// Problem dims
#define B_    32
#define CIN   32
#define COUT  64
#define H_    128
#define W_    128
#define HO_   126
#define WO_   126
#define MAXCN 64

typedef __attribute__((ext_vector_type(8))) short short8;
typedef __attribute__((ext_vector_type(4))) float floatx4;

static __device__ __forceinline__ unsigned short f2bf(float f) {
    union { float f; unsigned u; } v; v.f = f;
    unsigned r = v.u + 0x7fff + ((v.u >> 16) & 1);   // round-to-nearest-even
    return (unsigned short)(r >> 16);
}

// ---------------------------------------------------------------------------
// Fold masked 64-slot bank -> dense bf16 weights wk[tap][oc][c] (c-inner).
// slot j feeds channel j%32, active iff j < cn[oc]. 36 KB, L2-resident for
// the conv kernel.
// ---------------------------------------------------------------------------
__global__ void fold_bf16(const float* __restrict__ w,
                          const int* __restrict__ cn,
                          unsigned short* __restrict__ wk) {
    int idx = blockIdx.x * 256 + threadIdx.x;        // over 9*64*32 = 18432
    if (idx >= 9 * COUT * CIN) return;
    int c   = idx & 31;
    int oc  = (idx >> 5) & 63;
    int tap = idx >> 11;
    int n = cn[oc];
    float v = 0.0f;
    if (c < n)      v += w[(oc * MAXCN + c) * 9 + tap];
    if (c + 32 < n) v += w[(oc * MAXCN + c + 32) * 9 + tap];
    wk[idx] = f2bf(v);
}

// ---------------------------------------------------------------------------
// Fused implicit-GEMM conv, bf16 MFMA 16x16x32, reads NCHW fp32 x directly.
//   block: 16x16 output pixels x 32 oc (ocg = blockIdx.y). 4 waves; wave w
//   owns output rows 4w..4w+3. A = weights (m=oc) loaded per-tap straight
//   from global wk (36 KB, L2-resident, no LDS); B = pixels (n=col) from xs.
// LDS: ONLY xs[18*18][32] bf16 = 20736 B -> 6-7 blocks/CU (was 4 at 39 KB).
// Staging: thread = (pixel, channel-octet): 8 strided fp32 loads (16-lane
//   runs of consecutive ix -> coalesced), f2bf, pack, one ds_write_b128;
//   consecutive lanes -> consecutive 16 B -> conflict-free.
// Frag reads: const + l16*64B + quad*16B -> contiguous 1 KiB/wave.
// ---------------------------------------------------------------------------
__global__ __launch_bounds__(256, 6)
void conv_fused(const float* __restrict__ x,
                const unsigned short* __restrict__ wk,
                const float* __restrict__ bias,
                float* __restrict__ out) {
    __shared__ __align__(16) unsigned short xs[18 * 18 * 32];   // 20736 B

    const int tile = blockIdx.x;          // 0..63
    const int ocg  = blockIdx.y;          // 0..1
    const int b    = blockIdx.z;
    const int tx = tile & 7, ty = tile >> 3;
    const int x0 = tx * 16, y0 = ty * 16;
    const int tid = threadIdx.x;

    // ---- stage input tile from NCHW fp32, converting to bf16 ----
    const float* xb = x + (size_t)b * CIN * H_ * W_;
    uint4* xs4 = (uint4*)xs;
    for (int idx = tid; idx < 1296; idx += 256) {
        int pix = idx >> 2, c8 = idx & 3;            // pixel 0..323, octet 0..3
        int yy = pix / 18, xc = pix - yy * 18;
        int iy = y0 + yy; if (iy > H_ - 1) iy = H_ - 1;   // clamped rows feed
        int ix = x0 + xc; if (ix > W_ - 1) ix = W_ - 1;   // only unstored out
        const float* s = xb + (size_t)(c8 * 8) * (H_ * W_) + (size_t)iy * W_ + ix;
        union { unsigned short u16[8]; uint4 u4; } v;
#pragma unroll
        for (int j = 0; j < 8; ++j)
            v.u16[j] = f2bf(s[(size_t)j * (H_ * W_)]);
        xs4[idx] = v.u4;                             // lane-consecutive 16 B
    }
    __syncthreads();

    const int w_id = tid >> 6;
    const int lane = tid & 63;
    const int quad = lane >> 4, l16 = lane & 15;

    floatx4 acc[4][2];
#pragma unroll
    for (int i = 0; i < 4; ++i)
#pragma unroll
        for (int t = 0; t < 2; ++t) acc[i][t] = (floatx4)0.0f;

#pragma unroll
    for (int kh = 0; kh < 3; ++kh) {
#pragma unroll
        for (int kw = 0; kw < 3; ++kw) {
            const int tap = kh * 3 + kw;
            short8 a[2], bf[4];
#pragma unroll
            for (int t = 0; t < 2; ++t)
                a[t] = *(const short8*)&wk[((size_t)tap * 64 + ocg * 32 + t * 16 + l16) * 32 + quad * 8];
#pragma unroll
            for (int i = 0; i < 4; ++i)
                bf[i] = *(const short8*)&xs[(((4 * w_id + i + kh) * 18 + l16 + kw) * 32) + quad * 8];
#pragma unroll
            for (int i = 0; i < 4; ++i)
#pragma unroll
                for (int t = 0; t < 2; ++t)
                    acc[i][t] = __builtin_amdgcn_mfma_f32_16x16x32_bf16(a[t], bf[i], acc[i][t], 0, 0, 0);
        }
    }

    // ---- epilogue: +bias, guarded stores (quad-coalesced 64 B segments) ----
    const int col = x0 + l16;
#pragma unroll
    for (int i = 0; i < 4; ++i) {
        const int y = y0 + 4 * w_id + i;
        if (y >= HO_ || col >= WO_) continue;
#pragma unroll
        for (int t = 0; t < 2; ++t) {
#pragma unroll
            for (int r = 0; r < 4; ++r) {
                const int oc = ocg * 32 + t * 16 + quad * 4 + r;
                out[(((size_t)b * COUT + oc) * HO_ + y) * WO_ + col] =
                    acc[i][t][r] + bias[((size_t)oc * HO_ + y) * WO_ + col];
            }
        }
    }
}

// ===========================================================================
// Fallback fp32 path (proven in round 1) — used only if ws_size can't hold
// the 36 KB folded-weight buffer... and it needs 73 KB itself, so really
// only if ws is tiny-but-present. Kept for safety.
// ===========================================================================
__global__ void fold_kernel(const float* __restrict__ w,
                            const int* __restrict__ cn,
                            float* __restrict__ kd) {
    int idx = blockIdx.x * blockDim.x + threadIdx.x;
    if (idx >= COUT * CIN * 9) return;
    int t = idx % 9;
    int c = (idx / 9) % CIN;
    int o = idx / (9 * CIN);
    int n = cn[o];
    float v = 0.0f;
    if (c < n)      v += w[(o * MAXCN + c) * 9 + t];
    if (c + 32 < n) v += w[(o * MAXCN + c + 32) * 9 + t];
    kd[idx] = v;
}

__global__ __launch_bounds__(256)
void conv_kernel(const float* __restrict__ x,
                 const float* __restrict__ kd,
                 const float* __restrict__ bias,
                 float* __restrict__ out) {
    __shared__ __align__(16) float xsh[CIN * 18 * 20];
    __shared__ __align__(16) float wsh[16 * 289];
    const int b = blockIdx.z, ocg = blockIdx.y, tile = blockIdx.x;
    const int ty = tile >> 3, txx = tile & 7;
    const int y0 = ty * 16, x0 = txx * 16;
    const int tid = threadIdx.x;
    const float* xbp = x + (size_t)b * CIN * H_ * W_;
    for (int idx = tid; idx < CIN * 18 * 18; idx += 256) {
        int c = idx / 324, rem = idx - c * 324, r = rem / 18, col = rem - r * 18;
        int iy = y0 + r;   if (iy > H_ - 1) iy = H_ - 1;
        int ix = x0 + col; if (ix > W_ - 1) ix = W_ - 1;
        xsh[c * 360 + r * 20 + col] = xbp[(c * H_ + iy) * W_ + ix];
    }
    for (int idx = tid; idx < 16 * 288; idx += 256) {
        int oc = idx / 288, rr = idx - oc * 288;
        wsh[oc * 289 + rr] = kd[(ocg * 16 + oc) * 288 + rr];
    }
    __syncthreads();
    const int oc_l = tid & 15, pb = tid >> 4, pby = pb >> 2, pbx = pb & 3;
    float acc[4][4];
#pragma unroll
    for (int i = 0; i < 4; ++i)
#pragma unroll
        for (int j = 0; j < 4; ++j) acc[i][j] = 0.0f;
    const float* xp = &xsh[(pby * 4) * 20 + pbx * 4];
    const float* wp = &wsh[oc_l * 289];
    for (int c = 0; c < CIN; ++c) {
        float xr[6][6];
#pragma unroll
        for (int r = 0; r < 6; ++r) {
            const float* row = xp + c * 360 + r * 20;
            float4 v4 = *reinterpret_cast<const float4*>(row);
            float2 v2 = *reinterpret_cast<const float2*>(row + 4);
            xr[r][0] = v4.x; xr[r][1] = v4.y; xr[r][2] = v4.z;
            xr[r][3] = v4.w; xr[r][4] = v2.x; xr[r][5] = v2.y;
        }
        float wr[9];
#pragma unroll
        for (int t = 0; t < 9; ++t) wr[t] = wp[c * 9 + t];
#pragma unroll
        for (int kh = 0; kh < 3; ++kh)
#pragma unroll
            for (int kw = 0; kw < 3; ++kw) {
                const float wv = wr[kh * 3 + kw];
#pragma unroll
                for (int i = 0; i < 4; ++i)
#pragma unroll
                    for (int j = 0; j < 4; ++j)
                        acc[i][j] = fmaf(xr[i + kh][j + kw], wv, acc[i][j]);
            }
    }
    const int o = ocg * 16 + oc_l;
    const int yb = y0 + pby * 4, xq0 = x0 + pbx * 4;
    float* ob = out + ((size_t)(b * COUT + o)) * HO_ * WO_;
    const float* bb = bias + (size_t)o * HO_ * WO_;
#pragma unroll
    for (int i = 0; i < 4; ++i) {
        int y = yb + i;
        if (y >= HO_) continue;
#pragma unroll
        for (int j = 0; j < 4; ++j) {
            int xq = xq0 + j;
            if (xq >= WO_) continue;
            ob[y * WO_ + xq] = acc[i][j] + bb[y * WO_ + xq];
        }
    }
}

extern "C" void kernel_launch(void* const* d_in, const int* in_sizes, int n_in,
                              void* d_out, int out_size, void* d_ws, size_t ws_size,
                              hipStream_t stream) {
    const float* x    = (const float*)d_in[0];
    const float* w    = (const float*)d_in[1];
    const float* bias = (const float*)d_in[2];
    const int*   cn   = (const int*)d_in[3];
    float* out = (float*)d_out;

    const size_t WK_BYTES = (size_t)9 * COUT * CIN * 2;       // 36864

    if (ws_size >= WK_BYTES) {
        unsigned short* wkb = (unsigned short*)d_ws;
        fold_bf16<<<(9 * COUT * CIN + 255) / 256, 256, 0, stream>>>(w, cn, wkb);
        conv_fused<<<dim3(64, 2, B_), 256, 0, stream>>>(x, wkb, bias, out);
    } else {
        float* kd = (float*)d_ws;
        fold_kernel<<<(COUT * CIN * 9 + 255) / 256, 256, 0, stream>>>(w, cn, kd);
        dim3 grid(64, 4, B_);
        conv_kernel<<<grid, 256, 0, stream>>>(x, kd, bias, out);
    }
}